// Round 1
// baseline (373.122 us; speedup 1.0000x reference)
//
#include <hip/hip_runtime.h>
#include <hip/hip_bf16.h>

typedef unsigned short u16;
typedef __bf16 bf16x8 __attribute__((ext_vector_type(8)));
typedef float f32x4 __attribute__((ext_vector_type(4)));

__device__ __forceinline__ f32x4 mfma16(bf16x8 a, bf16x8 b, f32x4 c) {
    return __builtin_amdgcn_mfma_f32_16x16x32_bf16(a, b, c, 0, 0, 0);
}

// fp32 -> bf16 bits, round-to-nearest-even
__device__ __forceinline__ u16 f2b(float x) {
    union { float f; unsigned u; } a; a.f = x;
    unsigned r = a.u + 0x7fffu + ((a.u >> 16) & 1u);
    return (u16)(r >> 16);
}

// ---------------- cast fp32 -> bf16 ----------------
__global__ __launch_bounds__(256) void k_cast(const float* __restrict__ src,
                                              u16* __restrict__ dst, int n) {
    int i = (blockIdx.x * 256 + threadIdx.x) * 4;
    if (i >= n) return;
    float4 f = *(const float4*)&src[i];
    u16 o[4] = { f2b(f.x), f2b(f.y), f2b(f.z), f2b(f.w) };
    *(uint2*)&dst[i] = *(uint2*)o;
}

// ---------------- QKV GEMM: [8192,512] x [1536,512]^T -> q,k,v [B,H,S,64] bf16 ----
// q pre-scaled by 0.125 (exact in bf16 domain since applied in fp32 then rounded once)
__global__ __launch_bounds__(256) void k_gemm_qkv(const u16* __restrict__ xb,
                                                  const u16* __restrict__ wb,
                                                  const float* __restrict__ bias,
                                                  u16* __restrict__ qkvout) {
    __shared__ u16 As[128][40];
    __shared__ u16 Ws[64][40];
    const int tid = threadIdx.x;
    const int w = tid >> 6, lane = tid & 63, l15 = lane & 15, quad = lane >> 4;
    const int mb = blockIdx.x * 128, nb = blockIdx.y * 64;

    f32x4 acc[2][4];
#pragma unroll
    for (int i = 0; i < 2; i++)
#pragma unroll
        for (int j = 0; j < 4; j++) acc[i][j] = (f32x4){0.f, 0.f, 0.f, 0.f};

    for (int k0 = 0; k0 < 512; k0 += 32) {
        {
            int row = tid >> 1, cc = (tid & 1) * 16;
            const u16* g = &xb[(size_t)(mb + row) * 512 + k0 + cc];
            *(uint4*)&As[row][cc]     = *(const uint4*)g;
            *(uint4*)&As[row][cc + 8] = *(const uint4*)(g + 8);
            int wrow = tid >> 2, wcc = (tid & 3) * 8;
            *(uint4*)&Ws[wrow][wcc] = *(const uint4*)&wb[(size_t)(nb + wrow) * 512 + k0 + wcc];
        }
        __syncthreads();
        bf16x8 a0 = *(const bf16x8*)&As[w * 32 + l15][quad * 8];
        bf16x8 a1 = *(const bf16x8*)&As[w * 32 + 16 + l15][quad * 8];
#pragma unroll
        for (int nt = 0; nt < 4; nt++) {
            bf16x8 bfr = *(const bf16x8*)&Ws[nt * 16 + l15][quad * 8];
            acc[0][nt] = mfma16(a0, bfr, acc[0][nt]);
            acc[1][nt] = mfma16(a1, bfr, acc[1][nt]);
        }
        __syncthreads();
    }
    // epilogue: scatter to q/k/v [B=2][H=8][S=4096][64]
    const int seg = nb >> 9;          // 0=q 1=k 2=v (nb is 64-aligned, block stays in one seg)
    const int hh  = (nb >> 6) & 7;
    u16* obase = qkvout + (size_t)seg * (16ull * 4096 * 64);
    const float sc = (seg == 0) ? 0.125f : 1.0f;
#pragma unroll
    for (int mt = 0; mt < 2; mt++)
#pragma unroll
        for (int nt = 0; nt < 4; nt++)
#pragma unroll
            for (int r = 0; r < 4; r++) {
                int m = mb + w * 32 + mt * 16 + quad * 4 + r;
                int dloc = nt * 16 + l15;
                float vv = (acc[mt][nt][r] + bias[nb + dloc]) * sc;
                int b = m >> 12, s = m & 4095;
                obase[((size_t)((b * 8 + hh) * 4096 + s)) * 64 + dloc] = f2b(vv);
            }
}

// ---------------- flash attention (inverted-window mask) -----------------
// grid: (64 q-tiles, 16 bh). block: 256 = 4 waves x 16 q-rows. K-tile = 64.
__global__ __launch_bounds__(256) void k_attn(const u16* __restrict__ qkv,
                                              u16* __restrict__ ctx,
                                              const int* __restrict__ win) {
    __shared__ u16 Ks[64][72];   // [key][d]
    __shared__ u16 Vt[64][72];   // [d][key]  (transposed at staging)
    __shared__ u16 Ps[64][72];   // [q-row][key], per-wave 16-row slabs
    const int tid = threadIdx.x;
    const int w = tid >> 6, lane = tid & 63, l15 = lane & 15, quad = lane >> 4;
    const int bh = blockIdx.y;
    const int qb0 = blockIdx.x * 64;
    const int W = win[0];
    const u16* q = qkv;
    const u16* k = qkv + 16ull * 4096 * 64;
    const u16* v = qkv + 32ull * 4096 * 64;
    const size_t bhbase = (size_t)bh * 4096 * 64;

    const u16* qrow = q + bhbase + (size_t)(qb0 + w * 16 + l15) * 64;
    bf16x8 qf0 = *(const bf16x8*)&qrow[quad * 8];
    bf16x8 qf1 = *(const bf16x8*)&qrow[quad * 8 + 32];

    f32x4 O[4];
#pragma unroll
    for (int nt = 0; nt < 4; nt++) O[nt] = (f32x4){0.f, 0.f, 0.f, 0.f};
    float mrow[4] = {-1e30f, -1e30f, -1e30f, -1e30f};
    float lsum[4] = {0.f, 0.f, 0.f, 0.f};

    for (int kb = 0; kb < 4096; kb += 64) {
        int maxd = max(qb0 + 63 - kb, kb + 63 - qb0);
        if (maxd <= W) continue;  // tile fully inside window -> fully masked (uniform)
        bool partial = (kb <= qb0 + 63 + W) && (kb + 63 >= qb0 - W);
        {   // stage K row-major, V transposed
            int row = tid >> 2;
            int cc = (tid & 3) * 16;
            const u16* kg = &k[bhbase + (size_t)(kb + row) * 64 + cc];
            *(uint4*)&Ks[row][cc]     = *(const uint4*)kg;
            *(uint4*)&Ks[row][cc + 8] = *(const uint4*)(kg + 8);
            const u16* vg = &v[bhbase + (size_t)(kb + row) * 64 + cc];
            u16 tmp[16];
            *(uint4*)&tmp[0] = *(const uint4*)vg;
            *(uint4*)&tmp[8] = *(const uint4*)(vg + 8);
#pragma unroll
            for (int e = 0; e < 16; e++) Vt[cc + e][row] = tmp[e];
        }
        __syncthreads();
        // S = Q K^T (q pre-scaled by 1/8)
        f32x4 S[4];
#pragma unroll
        for (int nt = 0; nt < 4; nt++) {
            bf16x8 kf0 = *(const bf16x8*)&Ks[nt * 16 + l15][quad * 8];
            bf16x8 kf1 = *(const bf16x8*)&Ks[nt * 16 + l15][quad * 8 + 32];
            f32x4 z = {0.f, 0.f, 0.f, 0.f};
            S[nt] = mfma16(qf0, kf0, z);
            S[nt] = mfma16(qf1, kf1, S[nt]);
        }
        if (partial) {
#pragma unroll
            for (int nt = 0; nt < 4; nt++)
#pragma unroll
                for (int r = 0; r < 4; r++) {
                    int i = qb0 + w * 16 + quad * 4 + r;
                    int j = kb + nt * 16 + l15;
                    int dd = i - j; dd = dd < 0 ? -dd : dd;
                    if (dd <= W) S[nt][r] = -1e30f;  // finite sentinel: no NaN, wiped by alpha later
                }
        }
        // online softmax: rows live in 16-lane groups (quad owns rows quad*4+r)
        float rmax[4];
#pragma unroll
        for (int r = 0; r < 4; r++)
            rmax[r] = fmaxf(fmaxf(S[0][r], S[1][r]), fmaxf(S[2][r], S[3][r]));
#pragma unroll
        for (int off = 1; off < 16; off <<= 1)
#pragma unroll
            for (int r = 0; r < 4; r++) rmax[r] = fmaxf(rmax[r], __shfl_xor(rmax[r], off));
        float alpha[4], rsum[4];
#pragma unroll
        for (int r = 0; r < 4; r++) {
            float mn = fmaxf(mrow[r], rmax[r]);
            alpha[r] = __expf(mrow[r] - mn);
            mrow[r] = mn;
            rsum[r] = 0.f;
        }
#pragma unroll
        for (int nt = 0; nt < 4; nt++)
#pragma unroll
            for (int r = 0; r < 4; r++) {
                float p = __expf(S[nt][r] - mrow[r]);
                S[nt][r] = p;
                rsum[r] += p;
            }
#pragma unroll
        for (int off = 1; off < 16; off <<= 1)
#pragma unroll
            for (int r = 0; r < 4; r++) rsum[r] += __shfl_xor(rsum[r], off);
#pragma unroll
        for (int r = 0; r < 4; r++) lsum[r] = lsum[r] * alpha[r] + rsum[r];
        // P: C-layout -> LDS -> A-layout (verified m120 pattern); wave-local slab
#pragma unroll
        for (int nt = 0; nt < 4; nt++)
#pragma unroll
            for (int r = 0; r < 4; r++)
                Ps[w * 16 + quad * 4 + r][nt * 16 + l15] = f2b(S[nt][r]);
#pragma unroll
        for (int nt = 0; nt < 4; nt++)
#pragma unroll
            for (int r = 0; r < 4; r++) O[nt][r] *= alpha[r];
        // O += P V
#pragma unroll
        for (int ks = 0; ks < 2; ks++) {
            bf16x8 pa = *(const bf16x8*)&Ps[w * 16 + l15][ks * 32 + quad * 8];
#pragma unroll
            for (int nt = 0; nt < 4; nt++) {
                bf16x8 vb = *(const bf16x8*)&Vt[nt * 16 + l15][ks * 32 + quad * 8];
                O[nt] = mfma16(pa, vb, O[nt]);
            }
        }
        __syncthreads();
    }
    // epilogue: ctx[b][s][h*64+d] bf16
    int b = bh >> 3, h = bh & 7;
#pragma unroll
    for (int r = 0; r < 4; r++) {
        float inv = 1.0f / lsum[r];
        int qr = qb0 + w * 16 + quad * 4 + r;
        size_t rowoff = ((size_t)(b * 4096 + qr)) * 512 + h * 64;
#pragma unroll
        for (int nt = 0; nt < 4; nt++)
            ctx[rowoff + nt * 16 + l15] = f2b(O[nt][r] * inv);
    }
}

// ---------------- out GEMM: [8192,512] x [512,512]^T + bias -> fp32 ----------------
__global__ __launch_bounds__(256) void k_gemm_out(const u16* __restrict__ ab,
                                                  const u16* __restrict__ wb,
                                                  const float* __restrict__ bias,
                                                  float* __restrict__ out) {
    __shared__ u16 As[128][40];
    __shared__ u16 Ws[64][40];
    const int tid = threadIdx.x;
    const int w = tid >> 6, lane = tid & 63, l15 = lane & 15, quad = lane >> 4;
    const int mb = blockIdx.x * 128, nb = blockIdx.y * 64;

    f32x4 acc[2][4];
#pragma unroll
    for (int i = 0; i < 2; i++)
#pragma unroll
        for (int j = 0; j < 4; j++) acc[i][j] = (f32x4){0.f, 0.f, 0.f, 0.f};

    for (int k0 = 0; k0 < 512; k0 += 32) {
        {
            int row = tid >> 1, cc = (tid & 1) * 16;
            const u16* g = &ab[(size_t)(mb + row) * 512 + k0 + cc];
            *(uint4*)&As[row][cc]     = *(const uint4*)g;
            *(uint4*)&As[row][cc + 8] = *(const uint4*)(g + 8);
            int wrow = tid >> 2, wcc = (tid & 3) * 8;
            *(uint4*)&Ws[wrow][wcc] = *(const uint4*)&wb[(size_t)(nb + wrow) * 512 + k0 + wcc];
        }
        __syncthreads();
        bf16x8 a0 = *(const bf16x8*)&As[w * 32 + l15][quad * 8];
        bf16x8 a1 = *(const bf16x8*)&As[w * 32 + 16 + l15][quad * 8];
#pragma unroll
        for (int nt = 0; nt < 4; nt++) {
            bf16x8 bfr = *(const bf16x8*)&Ws[nt * 16 + l15][quad * 8];
            acc[0][nt] = mfma16(a0, bfr, acc[0][nt]);
            acc[1][nt] = mfma16(a1, bfr, acc[1][nt]);
        }
        __syncthreads();
    }
#pragma unroll
    for (int mt = 0; mt < 2; mt++)
#pragma unroll
        for (int nt = 0; nt < 4; nt++)
#pragma unroll
            for (int r = 0; r < 4; r++) {
                int m = mb + w * 32 + mt * 16 + quad * 4 + r;
                int n = nb + nt * 16 + l15;
                out[(size_t)m * 512 + n] = acc[mt][nt][r] + bias[n];
            }
}

extern "C" void kernel_launch(void* const* d_in, const int* in_sizes, int n_in,
                              void* d_out, int out_size, void* d_ws, size_t ws_size,
                              hipStream_t stream) {
    const float* x    = (const float*)d_in[0];
    const float* wqkv = (const float*)d_in[1];
    const float* bqkv = (const float*)d_in[2];
    const float* wout = (const float*)d_in[3];
    const float* bout = (const float*)d_in[4];
    const int*   win  = (const int*)d_in[5];
    float* out = (float*)d_out;

    // workspace layout (bf16 stored as u16); total ~44 MB
    u16* xb    = (u16*)d_ws;
    u16* wqkvb = xb    + 8192ull * 512;
    u16* woutb = wqkvb + 1536ull * 512;
    u16* qkvb  = woutb + 512ull * 512;
    u16* ctxb  = qkvb  + 3ull * 16 * 4096 * 64;

    k_cast<<<4096, 256, 0, stream>>>(x, xb, 8192 * 512);
    k_cast<<<768, 256, 0, stream>>>(wqkv, wqkvb, 1536 * 512);
    k_cast<<<256, 256, 0, stream>>>(wout, woutb, 512 * 512);
    k_gemm_qkv<<<dim3(64, 24), 256, 0, stream>>>(xb, wqkvb, bqkv, qkvb);
    k_attn<<<dim3(64, 16), 256, 0, stream>>>(qkvb, ctxb, win);
    k_gemm_out<<<dim3(64, 8), 256, 0, stream>>>(ctxb, woutb, bout, out);
}

// Round 2
// 239.061 us; speedup vs baseline: 1.5608x; 1.5608x over previous
//
#include <hip/hip_runtime.h>
#include <hip/hip_bf16.h>

typedef unsigned short u16;
typedef __bf16 bf16x8 __attribute__((ext_vector_type(8)));
typedef float f32x4 __attribute__((ext_vector_type(4)));

__device__ __forceinline__ f32x4 mfma16(bf16x8 a, bf16x8 b, f32x4 c) {
    return __builtin_amdgcn_mfma_f32_16x16x32_bf16(a, b, c, 0, 0, 0);
}

// fp32 -> bf16 bits, round-to-nearest-even
__device__ __forceinline__ u16 f2b(float x) {
    union { float f; unsigned u; } a; a.f = x;
    unsigned r = a.u + 0x7fffu + ((a.u >> 16) & 1u);
    return (u16)(r >> 16);
}

// ---------------- cast fp32 -> bf16 ----------------
__global__ __launch_bounds__(256) void k_cast(const float* __restrict__ src,
                                              u16* __restrict__ dst, int n) {
    int i = (blockIdx.x * 256 + threadIdx.x) * 4;
    if (i >= n) return;
    float4 f = *(const float4*)&src[i];
    u16 o[4] = { f2b(f.x), f2b(f.y), f2b(f.z), f2b(f.w) };
    *(uint2*)&dst[i] = *(uint2*)o;
}

// ---------------- QKV GEMM: [8192,512] x [1536,512]^T -> q,k [B,H,S,64], v [B,H,64,S] ----
// q pre-scaled by 0.125/ln(2) so attention can use exp2 directly.
__global__ __launch_bounds__(256) void k_gemm_qkv(const u16* __restrict__ xb,
                                                  const u16* __restrict__ wb,
                                                  const float* __restrict__ bias,
                                                  u16* __restrict__ qkvout) {
    __shared__ u16 As[128][40];
    __shared__ u16 Ws[64][40];
    const int tid = threadIdx.x;
    const int w = tid >> 6, lane = tid & 63, l15 = lane & 15, quad = lane >> 4;
    const int mb = blockIdx.x * 128, nb = blockIdx.y * 64;

    f32x4 acc[2][4];
#pragma unroll
    for (int i = 0; i < 2; i++)
#pragma unroll
        for (int j = 0; j < 4; j++) acc[i][j] = (f32x4){0.f, 0.f, 0.f, 0.f};

    for (int k0 = 0; k0 < 512; k0 += 32) {
        {
            int row = tid >> 1, cc = (tid & 1) * 16;
            const u16* g = &xb[(size_t)(mb + row) * 512 + k0 + cc];
            *(uint4*)&As[row][cc]     = *(const uint4*)g;
            *(uint4*)&As[row][cc + 8] = *(const uint4*)(g + 8);
            int wrow = tid >> 2, wcc = (tid & 3) * 8;
            *(uint4*)&Ws[wrow][wcc] = *(const uint4*)&wb[(size_t)(nb + wrow) * 512 + k0 + wcc];
        }
        __syncthreads();
        bf16x8 a0 = *(const bf16x8*)&As[w * 32 + l15][quad * 8];
        bf16x8 a1 = *(const bf16x8*)&As[w * 32 + 16 + l15][quad * 8];
#pragma unroll
        for (int nt = 0; nt < 4; nt++) {
            bf16x8 bfr = *(const bf16x8*)&Ws[nt * 16 + l15][quad * 8];
            acc[0][nt] = mfma16(a0, bfr, acc[0][nt]);
            acc[1][nt] = mfma16(a1, bfr, acc[1][nt]);
        }
        __syncthreads();
    }
    // epilogue: q,k -> [B*H][S][64]; v -> transposed [B*H][64][S]
    const int seg = nb >> 9;          // 0=q 1=k 2=v
    const int hh  = (nb >> 6) & 7;
    u16* obase = qkvout + (size_t)seg * (16ull * 4096 * 64);
    if (seg < 2) {
        const float sc = (seg == 0) ? 0.125f * 1.44269504088896340736f : 1.0f;
#pragma unroll
        for (int mt = 0; mt < 2; mt++)
#pragma unroll
            for (int nt = 0; nt < 4; nt++)
#pragma unroll
                for (int r = 0; r < 4; r++) {
                    int m = mb + w * 32 + mt * 16 + quad * 4 + r;
                    int dloc = nt * 16 + l15;
                    float vv = (acc[mt][nt][r] + bias[nb + dloc]) * sc;
                    int b = m >> 12, s = m & 4095;
                    obase[((size_t)((b * 8 + hh) * 4096 + s)) * 64 + dloc] = f2b(vv);
                }
    } else {
#pragma unroll
        for (int mt = 0; mt < 2; mt++)
#pragma unroll
            for (int nt = 0; nt < 4; nt++) {
                int m0 = mb + w * 32 + mt * 16 + quad * 4;
                int b = m0 >> 12, s0 = m0 & 4095;
                int dloc = nt * 16 + l15;
                u16 o[4];
#pragma unroll
                for (int r = 0; r < 4; r++)
                    o[r] = f2b(acc[mt][nt][r] + bias[nb + dloc]);
                *(uint2*)&obase[((size_t)((b * 8 + hh) * 64 + dloc)) * 4096 + s0] = *(uint2*)o;
            }
    }
}

// ---------------- flash attention v2 (inverted-window mask) -----------------
// block = 128 threads = 2 waves; each wave owns 32 q-rows (2 groups of 16).
// S^T = K*Q^T (Q register-resident), fixed-max softmax (exp2, no running max),
// deferred row-sum, packed b64 P stores, V pre-transposed in global.
__global__ __launch_bounds__(128) void k_attn(const u16* __restrict__ qkv,
                                              u16* __restrict__ ctx,
                                              const int* __restrict__ win) {
    __shared__ u16 Ks[64][72];   // [key][d]
    __shared__ u16 Vt[64][72];   // [d][key]
    __shared__ u16 Ps[64][72];   // [qrow local][key], per-wave 32-row slabs
    const int tid = threadIdx.x;
    const int w = tid >> 6, lane = tid & 63, l15 = lane & 15, quad = lane >> 4;
    const int bh = blockIdx.y;
    const int qb0 = blockIdx.x * 64;
    const int W = win[0];
    const u16* qg = qkv;
    const u16* kg = qkv + 16ull * 4096 * 64;
    const u16* vg = qkv + 32ull * 4096 * 64;   // [bh][64][4096]
    const size_t bhb = (size_t)bh * 4096 * 64;

    // Q fragments: B-operand of S^T = K*Q^T  (lane l15 = qrow within group)
    bf16x8 qf[2][2];
#pragma unroll
    for (int g = 0; g < 2; g++) {
        const u16* qrow = &qg[bhb + (size_t)(qb0 + w * 32 + g * 16 + l15) * 64];
        qf[g][0] = *(const bf16x8*)&qrow[quad * 8];
        qf[g][1] = *(const bf16x8*)&qrow[32 + quad * 8];
    }

    f32x4 O[2][4];
#pragma unroll
    for (int g = 0; g < 2; g++)
#pragma unroll
        for (int nt = 0; nt < 4; nt++) O[g][nt] = (f32x4){0.f, 0.f, 0.f, 0.f};
    float lsum[2] = {0.f, 0.f};

    const int srow = tid >> 1, shalf = (tid & 1) * 32;
    const u16* kgr = &kg[bhb + (size_t)srow * 64 + shalf];
    const u16* vgr = &vg[((size_t)bh * 64 + srow) * 4096 + shalf];

    for (int kb = 0; kb < 4096; kb += 64) {
        if (max(qb0 + 63 - kb, kb + 63 - qb0) <= W) continue;  // fully masked tile
        bool partial = (kb + 63 >= qb0 - W) && (kb <= qb0 + 63 + W);
        {   // stage K (row-major) and Vt (already d-major in global): all b128
            const u16* kp = kgr + (size_t)kb * 64;
            *(uint4*)&Ks[srow][shalf]      = *(const uint4*)kp;
            *(uint4*)&Ks[srow][shalf + 8]  = *(const uint4*)(kp + 8);
            *(uint4*)&Ks[srow][shalf + 16] = *(const uint4*)(kp + 16);
            *(uint4*)&Ks[srow][shalf + 24] = *(const uint4*)(kp + 24);
            const u16* vp = vgr + kb;
            *(uint4*)&Vt[srow][shalf]      = *(const uint4*)vp;
            *(uint4*)&Vt[srow][shalf + 8]  = *(const uint4*)(vp + 8);
            *(uint4*)&Vt[srow][shalf + 16] = *(const uint4*)(vp + 16);
            *(uint4*)&Vt[srow][shalf + 24] = *(const uint4*)(vp + 24);
        }
        __syncthreads();
        // S^T = K * Q^T : A = K frag (m=key), B = Q frag (n=qrow)
        f32x4 C[4][2];
#pragma unroll
        for (int nt = 0; nt < 4; nt++) {
            bf16x8 kf0 = *(const bf16x8*)&Ks[nt * 16 + l15][quad * 8];
            bf16x8 kf1 = *(const bf16x8*)&Ks[nt * 16 + l15][32 + quad * 8];
#pragma unroll
            for (int g = 0; g < 2; g++) {
                f32x4 z = (f32x4){0.f, 0.f, 0.f, 0.f};
                C[nt][g] = mfma16(kf0, qf[g][0], z);
                C[nt][g] = mfma16(kf1, qf[g][1], C[nt][g]);
            }
        }
        // p = 2^s (q pre-scaled by 1/(8 ln2)); masked -> 0; per-lane partial sums
        if (!partial) {
#pragma unroll
            for (int g = 0; g < 2; g++)
#pragma unroll
                for (int nt = 0; nt < 4; nt++) {
                    u16 o[4];
#pragma unroll
                    for (int r = 0; r < 4; r++) {
                        float p = __builtin_amdgcn_exp2f(C[nt][g][r]);
                        lsum[g] += p;
                        o[r] = f2b(p);
                    }
                    *(uint2*)&Ps[w * 32 + g * 16 + l15][nt * 16 + quad * 4] = *(uint2*)o;
                }
        } else {
#pragma unroll
            for (int g = 0; g < 2; g++) {
                int qr = qb0 + w * 32 + g * 16 + l15;
#pragma unroll
                for (int nt = 0; nt < 4; nt++) {
                    u16 o[4];
#pragma unroll
                    for (int r = 0; r < 4; r++) {
                        int key = kb + nt * 16 + quad * 4 + r;
                        int dd = qr - key; dd = dd < 0 ? -dd : dd;
                        float p = (dd <= W) ? 0.f : __builtin_amdgcn_exp2f(C[nt][g][r]);
                        lsum[g] += p;
                        o[r] = f2b(p);
                    }
                    *(uint2*)&Ps[w * 32 + g * 16 + l15][nt * 16 + quad * 4] = *(uint2*)o;
                }
            }
        }
        // O += P V   (A = P frag, B = V frag; V-frags reused across both g)
#pragma unroll
        for (int ks = 0; ks < 2; ks++) {
            bf16x8 pa0 = *(const bf16x8*)&Ps[w * 32 + l15][ks * 32 + quad * 8];
            bf16x8 pa1 = *(const bf16x8*)&Ps[w * 32 + 16 + l15][ks * 32 + quad * 8];
#pragma unroll
            for (int nt = 0; nt < 4; nt++) {
                bf16x8 vb = *(const bf16x8*)&Vt[nt * 16 + l15][ks * 32 + quad * 8];
                O[0][nt] = mfma16(pa0, vb, O[0][nt]);
                O[1][nt] = mfma16(pa1, vb, O[1][nt]);
            }
        }
        __syncthreads();
    }
    // finish deferred row-sums: reduce across the 4 quads (same l15)
#pragma unroll
    for (int g = 0; g < 2; g++) {
        lsum[g] += __shfl_xor(lsum[g], 16);
        lsum[g] += __shfl_xor(lsum[g], 32);
    }
    // epilogue: O rows are quad*4+r; lsum rows are l15 -> redistribute via shfl
    int b = bh >> 3, h = bh & 7;
#pragma unroll
    for (int g = 0; g < 2; g++)
#pragma unroll
        for (int r = 0; r < 4; r++) {
            float inv = 1.0f / __shfl(lsum[g], quad * 4 + r);
            int qr = qb0 + w * 32 + g * 16 + quad * 4 + r;
            size_t rowoff = ((size_t)(b * 4096 + qr)) * 512 + h * 64;
#pragma unroll
            for (int nt = 0; nt < 4; nt++)
                ctx[rowoff + nt * 16 + l15] = f2b(O[g][nt][r] * inv);
        }
}

// ---------------- out GEMM: [8192,512] x [512,512]^T + bias -> fp32 ----------------
__global__ __launch_bounds__(256) void k_gemm_out(const u16* __restrict__ ab,
                                                  const u16* __restrict__ wb,
                                                  const float* __restrict__ bias,
                                                  float* __restrict__ out) {
    __shared__ u16 As[128][40];
    __shared__ u16 Ws[64][40];
    const int tid = threadIdx.x;
    const int w = tid >> 6, lane = tid & 63, l15 = lane & 15, quad = lane >> 4;
    const int mb = blockIdx.x * 128, nb = blockIdx.y * 64;

    f32x4 acc[2][4];
#pragma unroll
    for (int i = 0; i < 2; i++)
#pragma unroll
        for (int j = 0; j < 4; j++) acc[i][j] = (f32x4){0.f, 0.f, 0.f, 0.f};

    for (int k0 = 0; k0 < 512; k0 += 32) {
        {
            int row = tid >> 1, cc = (tid & 1) * 16;
            const u16* g = &ab[(size_t)(mb + row) * 512 + k0 + cc];
            *(uint4*)&As[row][cc]     = *(const uint4*)g;
            *(uint4*)&As[row][cc + 8] = *(const uint4*)(g + 8);
            int wrow = tid >> 2, wcc = (tid & 3) * 8;
            *(uint4*)&Ws[wrow][wcc] = *(const uint4*)&wb[(size_t)(nb + wrow) * 512 + k0 + wcc];
        }
        __syncthreads();
        bf16x8 a0 = *(const bf16x8*)&As[w * 32 + l15][quad * 8];
        bf16x8 a1 = *(const bf16x8*)&As[w * 32 + 16 + l15][quad * 8];
#pragma unroll
        for (int nt = 0; nt < 4; nt++) {
            bf16x8 bfr = *(const bf16x8*)&Ws[nt * 16 + l15][quad * 8];
            acc[0][nt] = mfma16(a0, bfr, acc[0][nt]);
            acc[1][nt] = mfma16(a1, bfr, acc[1][nt]);
        }
        __syncthreads();
    }
#pragma unroll
    for (int mt = 0; mt < 2; mt++)
#pragma unroll
        for (int nt = 0; nt < 4; nt++)
#pragma unroll
            for (int r = 0; r < 4; r++) {
                int m = mb + w * 32 + mt * 16 + quad * 4 + r;
                int n = nb + nt * 16 + l15;
                out[(size_t)m * 512 + n] = acc[mt][nt][r] + bias[n];
            }
}

extern "C" void kernel_launch(void* const* d_in, const int* in_sizes, int n_in,
                              void* d_out, int out_size, void* d_ws, size_t ws_size,
                              hipStream_t stream) {
    const float* x    = (const float*)d_in[0];
    const float* wqkv = (const float*)d_in[1];
    const float* bqkv = (const float*)d_in[2];
    const float* wout = (const float*)d_in[3];
    const float* bout = (const float*)d_in[4];
    const int*   win  = (const int*)d_in[5];
    float* out = (float*)d_out;

    // workspace layout (bf16 stored as u16); total ~44 MB
    u16* xb    = (u16*)d_ws;
    u16* wqkvb = xb    + 8192ull * 512;
    u16* woutb = wqkvb + 1536ull * 512;
    u16* qkvb  = woutb + 512ull * 512;
    u16* ctxb  = qkvb  + 3ull * 16 * 4096 * 64;

    k_cast<<<4096, 256, 0, stream>>>(x, xb, 8192 * 512);
    k_cast<<<768, 256, 0, stream>>>(wqkv, wqkvb, 1536 * 512);
    k_cast<<<256, 256, 0, stream>>>(wout, woutb, 512 * 512);
    k_gemm_qkv<<<dim3(64, 24), 256, 0, stream>>>(xb, wqkvb, bqkv, qkvb);
    k_attn<<<dim3(64, 16), 128, 0, stream>>>(qkvb, ctxb, win);
    k_gemm_out<<<dim3(64, 8), 256, 0, stream>>>(ctxb, woutb, bout, out);
}